// Round 3
// baseline (551.129 us; speedup 1.0000x reference)
//
#include <hip/hip_runtime.h>
#include <hip/hip_bf16.h>
#include <cstdint>
#include <cstddef>

typedef unsigned short u16;
typedef unsigned int u32;
typedef __attribute__((ext_vector_type(8))) short bf16x8;
typedef __attribute__((ext_vector_type(4))) float f32x4;

static constexpr int Bb = 2, Ll = 2048, Dd = 1024, Hh = 16, Rr = 256, Ee = 8, Ff = 1024;
static constexpr int Tt = Bb * Ll;   // 4096 tokens
// softmax scale folded into q at the GEMM epilogue: 0.125 * log2(e)
static constexpr float QSCALE = 0.18033688011112042f;

__device__ __forceinline__ u16 f2bf(float f){
  union { float f; u32 u; } v; v.f = f;
  u32 u = v.u;
  u32 r = u + 0x7FFFu + ((u >> 16) & 1u);
  return (u16)(r >> 16);
}
__device__ __forceinline__ float bf2f(u16 b){
  union { u32 u; float f; } v; v.u = ((u32)b) << 16; return v.f;
}

// async global->LDS, 16B per lane. LDS dest wave-uniform base + lane*16. Full exec only.
#define GLDS(gp, lp) __builtin_amdgcn_global_load_lds( \
    (const __attribute__((address_space(1))) unsigned int*)(gp), \
    (__attribute__((address_space(3))) unsigned int*)(lp), 16, 0, 0)

// ---- batched transpose+convert for the five 1024x1024 non-expert weights ----
__global__ void transpose5(const float* __restrict__ q_w, const float* __restrict__ o_w,
                           const float* __restrict__ w1, const float* __restrict__ w3,
                           const float* __restrict__ w2,
                           u16* __restrict__ qkvdT, u16* __restrict__ oT,
                           u16* __restrict__ sh13T, u16* __restrict__ sh2T){
  const float* s; u16* d; int off, str;
  switch (blockIdx.z){
    case 0: s = q_w; d = qkvdT; off = 0; str = 1; break;
    case 1: s = o_w; d = oT;    off = 0; str = 1; break;
    case 2: s = w1;  d = sh13T; off = 0; str = 2; break;   // interleaved w1|w3
    case 3: s = w3;  d = sh13T; off = 1; str = 2; break;
    default: s = w2; d = sh2T;  off = 0; str = 1; break;
  }
  __shared__ float tile[32][33];
  int bx = blockIdx.x * 32, by = blockIdx.y * 32;
  int tx = threadIdx.x, ty = threadIdx.y;
  #pragma unroll
  for (int i = ty; i < 32; i += 8) tile[i][tx] = s[(size_t)(by + i) * 1024 + bx + tx];
  __syncthreads();
  #pragma unroll
  for (int i = ty; i < 32; i += 8)
    d[(size_t)(off + (bx + i) * str) * 1024 + by + tx] = f2bf(tile[tx][i]);
}

// ---- batched transpose+convert for the 24 expert weights ----
__global__ void transposeEx(const float* __restrict__ re_w1, const float* __restrict__ re_w3,
                            const float* __restrict__ re_w2,
                            u16* __restrict__ re13T, u16* __restrict__ re2T){
  int z = blockIdx.z, which = z >> 3, e = z & 7;
  const float* s; u16* d; int off, str;
  size_t eo = (size_t)e * 1024 * 1024;
  if (which == 0){ s = re_w1 + eo; d = re13T + (size_t)e * 2048 * 1024; off = 0; str = 2; }
  else if (which == 1){ s = re_w3 + eo; d = re13T + (size_t)e * 2048 * 1024; off = 1; str = 2; }
  else { s = re_w2 + eo; d = re2T + (size_t)e * 1024 * 1024; off = 0; str = 1; }
  __shared__ float tile[32][33];
  int bx = blockIdx.x * 32, by = blockIdx.y * 32;
  int tx = threadIdx.x, ty = threadIdx.y;
  #pragma unroll
  for (int i = ty; i < 32; i += 8) tile[i][tx] = s[(size_t)(by + i) * 1024 + bx + tx];
  __syncthreads();
  #pragma unroll
  for (int i = ty; i < 32; i += 8)
    d[(size_t)(off + (bx + i) * str) * 1024 + by + tx] = f2bf(tile[tx][i]);
}

// ---- generic transpose (kvd: K=1024,N=256 ; kvu: K=256,N=2048) ----
__global__ void transpose_conv(const float* __restrict__ src, u16* __restrict__ dst,
                               int K, int N, int dstOff){
  __shared__ float tile[32][33];
  int bx = blockIdx.x * 32, by = blockIdx.y * 32;
  int tx = threadIdx.x, ty = threadIdx.y;
  #pragma unroll
  for (int i = ty; i < 32; i += 8) tile[i][tx] = src[(size_t)(by + i) * N + bx + tx];
  __syncthreads();
  #pragma unroll
  for (int i = ty; i < 32; i += 8)
    dst[(size_t)(dstOff + bx + i) * K + by + tx] = f2bf(tile[tx][i]);
}

// ---- rmsnorm: fp32 in -> bf16 out ----
template<int DIM>
__global__ void rmsnorm_kernel(const float* __restrict__ x, const float* __restrict__ w,
                               u16* __restrict__ out){
  int t = blockIdx.x;
  const float* xr = x + (size_t)t * DIM;
  u16* orow = out + (size_t)t * DIM;
  int tid = threadIdx.x;
  constexpr int NT = 256;
  constexpr int PER = DIM / NT > 0 ? DIM / NT : 1;
  float vals[PER];
  float ss = 0.f;
  #pragma unroll
  for (int i = 0; i < PER; i++){
    int d = tid + i * NT;
    float v = (d < DIM) ? xr[d] : 0.f;
    vals[i] = v; ss += v * v;
  }
  __shared__ float red[4];
  for (int m = 32; m; m >>= 1) ss += __shfl_xor(ss, m, 64);
  if ((tid & 63) == 0) red[tid >> 6] = ss;
  __syncthreads();
  float tot = red[0] + red[1] + red[2] + red[3];
  float rn = rsqrtf(tot / DIM + 1e-6f);
  #pragma unroll
  for (int i = 0; i < PER; i++){
    int d = tid + i * NT;
    if (d < DIM) orow[d] = f2bf(vals[i] * rn * w[d]);
  }
}

// ---- router: fp32 rmsnorm(h)@gate, softmax, top2; ALSO writes hn (bf16) ----
__global__ void router_kernel(const float* __restrict__ h, const float* __restrict__ ln2w,
                              const float* __restrict__ gate,
                              float* __restrict__ probs_out,
                              int* __restrict__ topi, float* __restrict__ topw,
                              u16* __restrict__ hn){
  int t = blockIdx.x; int tid = threadIdx.x;
  const float* hr = h + (size_t)t * Dd;
  float v[4]; float ss = 0.f;
  #pragma unroll
  for (int i = 0; i < 4; i++){ float x = hr[tid + i * 256]; v[i] = x; ss += x * x; }
  __shared__ float red[4];
  for (int m = 32; m; m >>= 1) ss += __shfl_xor(ss, m, 64);
  if ((tid & 63) == 0) red[tid >> 6] = ss;
  __syncthreads();
  float rn = rsqrtf((red[0] + red[1] + red[2] + red[3]) / Dd + 1e-6f);
  float p[8];
  #pragma unroll
  for (int e = 0; e < 8; e++) p[e] = 0.f;
  #pragma unroll
  for (int i = 0; i < 4; i++){
    int d = tid + i * 256;
    float hv = v[i] * rn * ln2w[d];
    hn[(size_t)t * Dd + d] = f2bf(hv);
    const float* g = gate + (size_t)d * 8;
    #pragma unroll
    for (int e = 0; e < 8; e++) p[e] += hv * g[e];
  }
  #pragma unroll
  for (int e = 0; e < 8; e++){
    float x = p[e];
    for (int m = 32; m; m >>= 1) x += __shfl_xor(x, m, 64);
    p[e] = x;
  }
  __shared__ float pe[4][8];
  if ((tid & 63) == 0){ for (int e = 0; e < 8; e++) pe[tid >> 6][e] = p[e]; }
  __syncthreads();
  if (tid == 0){
    float lg[8];
    for (int e = 0; e < 8; e++) lg[e] = pe[0][e] + pe[1][e] + pe[2][e] + pe[3][e];
    float mx = lg[0];
    for (int e = 1; e < 8; e++) mx = fmaxf(mx, lg[e]);
    float pr[8]; float s = 0.f;
    for (int e = 0; e < 8; e++){ pr[e] = __expf(lg[e] - mx); s += pr[e]; }
    float inv = 1.f / s;
    for (int e = 0; e < 8; e++) probs_out[(size_t)t * 8 + e] = pr[e] * inv;
    int i0 = 0;
    for (int e = 1; e < 8; e++) if (pr[e] > pr[i0]) i0 = e;
    int i1 = -1;
    for (int e = 0; e < 8; e++){ if (e == i0) continue; if (i1 < 0 || pr[e] > pr[i1]) i1 = e; }
    float w0 = pr[i0], w1 = pr[i1]; float wn = 1.f / (w0 + w1);
    topi[t * 2] = i0; topi[t * 2 + 1] = i1;
    topw[t * 2] = w0 * wn; topw[t * 2 + 1] = w1 * wn;
  }
}

// ---- histogram of topi -> counts (LDS-aggregated) ----
__global__ void hist_kernel(const int* __restrict__ topi, int* __restrict__ counts){
  __shared__ int h[8];
  int tid = threadIdx.x;
  if (tid < 8) h[tid] = 0;
  __syncthreads();
  int base = blockIdx.x * 512;
  for (int i = tid; i < 512; i += 256) atomicAdd(&h[topi[base + i]], 1);
  __syncthreads();
  if (tid < 8) atomicAdd(&counts[tid], h[tid]);
}

// ---- bucket: LDS histogram + chunk reservation; offsets computed from counts ----
__global__ void bucket_kernel(const int* __restrict__ topi, const float* __restrict__ topw,
                              const int* __restrict__ counts, int* __restrict__ cur,
                              int* __restrict__ entries, float* __restrict__ ew){
  __shared__ int lh[8], lbase[8], lcur[8], loffs[8];
  int tid = threadIdx.x;
  if (tid < 8) lh[tid] = 0;
  __syncthreads();
  int t = blockIdx.x * 256 + tid;
  int e0 = topi[t * 2], e1 = topi[t * 2 + 1];
  atomicAdd(&lh[e0], 1); atomicAdd(&lh[e1], 1);
  __syncthreads();
  if (tid == 0){
    int c = 0;
    for (int e = 0; e < 8; e++){ loffs[e] = c; c += counts[e]; }
  }
  if (tid < 8){ lbase[tid] = atomicAdd(&cur[tid], lh[tid]); lcur[tid] = 0; }
  __syncthreads();
  int p0 = atomicAdd(&lcur[e0], 1);
  int pos0 = loffs[e0] + lbase[e0] + p0;
  entries[pos0] = t; ew[pos0] = topw[t * 2];
  int p1 = atomicAdd(&lcur[e1], 1);
  int pos1 = loffs[e1] + lbase[e1] + p1;
  entries[pos1] = t; ew[pos1] = topw[t * 2 + 1];
}

// ---- bf16 GEMM: C[M,N] = A[M,K] @ Bt[N,K]^T ; m97 structure, tile TM x 128, BK=32 ----
// ROWMODE: 0 dense; 1 gather rows via entries; 2 dense-in-entry-space (A row = off+r)
// MODE: 0 bf16 C; 1 f32 C = acc + res; 4 atomicAdd(out[token], w*acc);
//       5 split: col<1024 -> bf16 C scaled by QSCALE (q for attn, log2-domain softmax);
//                col>=1024 -> fp32 outAt (latent-pre, routing-critical)
//       6 swiglu: interleaved even/odd cols = (h1,h3); write silu(h1)*h3 bf16 at col>>1
template<int TM, int ROWMODE, int MODE>
__launch_bounds__(256)
__global__ void gemm_bt(const u16* __restrict__ A, const u16* __restrict__ Bt,
                        void* __restrict__ C, const float* __restrict__ res,
                        int M, int N, int K, int lda, int ldc,
                        const int* __restrict__ entries, const float* __restrict__ ew,
                        const int* __restrict__ counts,
                        float* __restrict__ outAt){
  constexpr int MTC = TM / 32;
  __shared__ __align__(16) u16 As[TM * 32];
  __shared__ __align__(16) u16 Bs[128 * 32];
  __shared__ int els[TM];
  __shared__ float ewl[TM];

  int e = (ROWMODE ? blockIdx.z : 0);
  const u16* Bte = Bt + (size_t)e * N * K;
  int cnt, off;
  if (ROWMODE == 0){ cnt = M; off = 0; }
  else {
    cnt = counts[e];
    off = 0;
    for (int i = 0; i < e; i++) off += counts[i];
  }
  int rt = blockIdx.y * TM;
  if (rt >= cnt) return;
  int cb = blockIdx.x * 128;
  int tid = threadIdx.x;

  if (ROWMODE >= 1){
    if (tid < TM){
      int r = rt + tid;
      els[tid] = (r < cnt) ? entries[off + r] : 0;
      ewl[tid] = (MODE == 4 && r < cnt) ? ew[off + r] : 0.f;
    }
    __syncthreads();
  }

  int sr = tid >> 2;
  int skc = (tid & 3) * 8;
  int rr0 = rt + sr, rr1 = rt + sr + 64;
  size_t ar0 = 0, ar1 = 0;
  if (ROWMODE == 0){ ar0 = (size_t)rr0; ar1 = (size_t)rr1; }
  else if (ROWMODE == 1){ ar0 = (size_t)els[sr];
                          ar1 = (TM == 128) ? (size_t)els[sr + 64] : 0; }
  else {
    int c0 = rr0 < cnt ? rr0 : (cnt - 1);
    int c1 = rr1 < cnt ? rr1 : (cnt - 1);
    ar0 = (size_t)off + c0; ar1 = (size_t)off + c1;
  }
  const u16* pa0 = A + ar0 * lda + skc;
  const u16* pa1 = A + ar1 * lda + skc;
  const u16* pb0 = Bte + (size_t)(cb + sr) * K + skc;
  const u16* pb1 = Bte + (size_t)(cb + sr + 64) * K + skc;
  u16* lA0 = &As[tid * 8];
  u16* lA1 = &As[(TM == 128 ? 2048 : 0) + tid * 8];
  u16* lB0 = &Bs[tid * 8];
  u16* lB1 = &Bs[2048 + tid * 8];

  int w = tid >> 6, lane = tid & 63;
  int wm = w >> 1, wn = w & 1;
  int quad = lane >> 4, l16 = lane & 15;

  f32x4 acc[MTC][4];
  const f32x4 zf = {0.f, 0.f, 0.f, 0.f};
  #pragma unroll
  for (int i = 0; i < MTC; i++)
    #pragma unroll
    for (int j = 0; j < 4; j++) acc[i][j] = zf;

  for (int k0 = 0; k0 < K; k0 += 32){
    __syncthreads();
    GLDS(pa0 + k0, lA0);
    if (TM == 128) GLDS(pa1 + k0, lA1);
    GLDS(pb0 + k0, lB0);
    GLDS(pb1 + k0, lB1);
    __syncthreads();
    bf16x8 af[MTC], bfr[4];
    #pragma unroll
    for (int mt = 0; mt < MTC; mt++)
      af[mt] = *(const bf16x8*)&As[(wm * (TM / 2) + mt * 16 + l16) * 32 + quad * 8];
    #pragma unroll
    for (int nt = 0; nt < 4; nt++)
      bfr[nt] = *(const bf16x8*)&Bs[(wn * 64 + nt * 16 + l16) * 32 + quad * 8];
    #pragma unroll
    for (int mt = 0; mt < MTC; mt++)
      #pragma unroll
      for (int nt = 0; nt < 4; nt++)
        acc[mt][nt] = __builtin_amdgcn_mfma_f32_16x16x32_bf16(af[mt], bfr[nt], acc[mt][nt], 0, 0, 0);
  }

  #pragma unroll
  for (int mt = 0; mt < MTC; mt++){
    #pragma unroll
    for (int nt = 0; nt < 4; nt++){
      #pragma unroll
      for (int r = 0; r < 4; r++){
        int row = wm * (TM / 2) + mt * 16 + quad * 4 + r;
        int col = cb + wn * 64 + nt * 16 + l16;
        int rr = rt + row;
        float v = acc[mt][nt][r];
        if (MODE == 6){
          float pv = __shfl_xor(v, 1, 64);      // partner col (all lanes execute)
          if (rr < cnt && (l16 & 1) == 0){
            float sl = v / (1.f + __expf(-v));
            size_t crow = (size_t)((ROWMODE == 1) ? (off + rr) : rr);
            ((u16*)C)[crow * ldc + (col >> 1)] = f2bf(sl * pv);
          }
          continue;
        }
        if (rr >= cnt) continue;
        if (MODE == 0){
          size_t ci = (size_t)((ROWMODE == 1) ? (off + rr) : rr) * ldc + col;
          ((u16*)C)[ci] = f2bf(v);
        } else if (MODE == 1){
          size_t ci = (size_t)rr * ldc + col;
          ((float*)C)[ci] = v + res[ci];
        } else if (MODE == 5){
          if (col < 1024) ((u16*)C)[(size_t)rr * 1024 + col] = f2bf(v * QSCALE);
          else            outAt[(size_t)rr * 256 + (col - 1024)] = v;
        } else {
          int tok = els[row];
          atomicAdd(&outAt[(size_t)tok * ldc + col], ewl[row] * v);
        }
      }
    }
  }
}

// ======== 256x256 8-phase grouped swiglu up-projection (T2+T3+T4+T5) ========
// z = expert: 0..7 routed (A rows gathered via entries, C = gr in entry space),
//             8 = shared (identity rows, C = shg).  N=2048 interleaved w1|w3,
//             K=1024, BK=64, 512 threads (2Mx4N waves), 128 KiB dbuf LDS.
// LDS XOR-swizzle applied source-side (pre-swizzled global addr, linear GLDS
// dest) and read-side: byte col ^= ((row&7)<<4)  -> conflict-free ds_read_b128.
// Schedule (T3+T4): per K-tile, 4 quadrant phases with raw barriers; tile t+2
// is staged into the just-freed buffer at phase 4; tile ends with a COUNTED
// s_waitcnt vmcnt(8) (drains t+1's loads, leaves t+2's in flight) -> the
// prefetch queue is never drained to 0 in the steady loop.
#define RBAR() __builtin_amdgcn_s_barrier()
#define VMCNT8() do{ asm volatile("s_waitcnt vmcnt(8)" ::: "memory"); \
                     __builtin_amdgcn_sched_barrier(0); }while(0)
#define VMCNT0() do{ asm volatile("s_waitcnt vmcnt(0)" ::: "memory"); \
                     __builtin_amdgcn_sched_barrier(0); }while(0)
#define MMQ(MQ, NQ, FA, FB) do{ \
  _Pragma("unroll") \
  for (int m4_ = 0; m4_ < 4; m4_++){ \
    _Pragma("unroll") \
    for (int n2_ = 0; n2_ < 2; n2_++){ \
      acc[(MQ)*4+m4_][(NQ)*2+n2_] = __builtin_amdgcn_mfma_f32_16x16x32_bf16(FA[m4_][0], FB[n2_][0], acc[(MQ)*4+m4_][(NQ)*2+n2_], 0, 0, 0); \
      acc[(MQ)*4+m4_][(NQ)*2+n2_] = __builtin_amdgcn_mfma_f32_16x16x32_bf16(FA[m4_][1], FB[n2_][1], acc[(MQ)*4+m4_][(NQ)*2+n2_], 0, 0, 0); \
    } \
  } }while(0)
#define RDA(DST, BB, MQ) do{ \
  _Pragma("unroll") \
  for (int m4_ = 0; m4_ < 4; m4_++){ \
    const char* p_ = (const char*)(&As[BB][0]) + (size_t)(wm*128 + (MQ)*64 + m4_*16 + l16)*128; \
    DST[m4_][0] = *(const bf16x8*)(p_ + offk0); \
    DST[m4_][1] = *(const bf16x8*)(p_ + offk1); \
  } }while(0)
#define RDB(DST, BB, NQ) do{ \
  _Pragma("unroll") \
  for (int n2_ = 0; n2_ < 2; n2_++){ \
    const char* p_ = (const char*)(&Bs[BB][0]) + (size_t)(wn*64 + (NQ)*32 + n2_*16 + l16)*128; \
    DST[n2_][0] = *(const bf16x8*)(p_ + offk0); \
    DST[n2_][1] = *(const bf16x8*)(p_ + offk1); \
  } }while(0)
#define STGA(SB, H, KT) do{ \
  GLDS(gA[(H)*2+0] + (size_t)(KT)*64, &As[SB][((H)*128 +  0)*64] + (size_t)tid*8); \
  GLDS(gA[(H)*2+1] + (size_t)(KT)*64, &As[SB][((H)*128 + 64)*64] + (size_t)tid*8); }while(0)
#define STGB(SB, H, KT) do{ \
  GLDS(gB[(H)*2+0] + (size_t)(KT)*64, &Bs[SB][((H)*128 +  0)*64] + (size_t)tid*8); \
  GLDS(gB[(H)*2+1] + (size_t)(KT)*64, &Bs[SB][((H)*128 + 64)*64] + (size_t)tid*8); }while(0)

__launch_bounds__(512, 2)
__global__ void gemm256_up(const u16* __restrict__ A,
                           const u16* __restrict__ sh13, const u16* __restrict__ re13,
                           u16* __restrict__ shg, u16* __restrict__ gr,
                           const int* __restrict__ entries, const int* __restrict__ counts){
  __shared__ __align__(16) u16 As[2][256 * 64];
  __shared__ __align__(16) u16 Bs[2][256 * 64];

  int e = blockIdx.z;
  int cnt, off = 0;
  if (e < 8){
    cnt = counts[e];
    for (int i = 0; i < e; i++) off += counts[i];
  } else cnt = Tt;
  int rt = blockIdx.y * 256;
  if (rt >= cnt) return;
  int cb = blockIdx.x * 256;
  const u16* Bte = (e < 8) ? (re13 + (size_t)e * 2048 * 1024) : sh13;
  u16* Cb = (e < 8) ? gr : shg;

  int tid = threadIdx.x;
  int w = tid >> 6, lane = tid & 63, quad = lane >> 4, l16 = lane & 15;
  int wm = w >> 2, wn = w & 3;                 // 2 x 4 wave grid
  int swz = (l16 & 7) << 4;                    // per-lane XOR (bytes)
  int offk0 = (quad * 16) ^ swz;               // ks=0 byte col (swizzled)
  int offk1 = (64 + quad * 16) ^ swz;          // ks=1

  // staging: thread covers row (i*64 + tid/8), 16B chunk (tid&7), src pre-swizzled
  int trow = tid >> 3;
  int sk = ((((tid & 7) << 4) ^ ((trow & 7) << 4)) >> 1);   // bf16 elems
  const u16* gA[4]; const u16* gB[4];
  #pragma unroll
  for (int i = 0; i < 4; i++){
    int r = i * 64 + trow;                     // tile row 0..255
    int garow;
    if (e < 8){
      int idx = rt + r; if (idx >= cnt) idx = cnt - 1;
      garow = entries[off + idx];
    } else garow = rt + r;
    gA[i] = A + (size_t)garow * 1024 + sk;
    gB[i] = Bte + (size_t)(cb + r) * 1024 + sk;
  }

  f32x4 acc[8][4];
  const f32x4 zf = {0.f, 0.f, 0.f, 0.f};
  #pragma unroll
  for (int i = 0; i < 8; i++)
    #pragma unroll
    for (int j = 0; j < 4; j++) acc[i][j] = zf;

  // K-tile body: 4 quadrant phases; stage tile t2 -> buf b during phase 4
  // (all reads of buf b are drained by each wave's own MFMA consumption
  //  before the phase-3-end barrier, so the overwrite is race-free).
  auto tile = [&](int b, int t2, bool stg){
    bf16x8 fa0[4][2], fa1[4][2], fb0[2][2], fb1[2][2];
    RDA(fa0, b, 0); RDB(fb0, b, 0);
    RBAR();
    __builtin_amdgcn_s_setprio(1); MMQ(0, 0, fa0, fb0); __builtin_amdgcn_s_setprio(0);
    RBAR();
    RDB(fb1, b, 1);
    RBAR();
    __builtin_amdgcn_s_setprio(1); MMQ(0, 1, fa0, fb1); __builtin_amdgcn_s_setprio(0);
    RBAR();
    RDA(fa1, b, 1);
    RBAR();
    __builtin_amdgcn_s_setprio(1); MMQ(1, 0, fa1, fb0); __builtin_amdgcn_s_setprio(0);
    RBAR();
    if (stg){ STGB(b, 0, t2); STGB(b, 1, t2); STGA(b, 0, t2); STGA(b, 1, t2); }
    __builtin_amdgcn_s_setprio(1); MMQ(1, 1, fa1, fb1); __builtin_amdgcn_s_setprio(0);
  };

  // prologue: stage tile 0 -> buf0, tile 1 -> buf1; wait only for tile 0
  STGB(0, 0, 0); STGB(0, 1, 0); STGA(0, 0, 0); STGA(0, 1, 0);
  STGB(1, 0, 1); STGB(1, 1, 1); STGA(1, 0, 1); STGA(1, 1, 1);
  VMCNT8();            // drain tile0's 8 loads; tile1's 8 stay in flight
  RBAR();

  for (int t = 0; t < 14; ++t){
    tile(t & 1, t + 2, true);
    VMCNT8();          // drain tile (t+1)'s 8; leave tile (t+2)'s 8 in flight
    RBAR();
  }
  tile(0, 0, false);   // t = 14 (buf0); only tile 15's loads outstanding
  VMCNT0();
  RBAR();
  tile(1, 0, false);   // t = 15 (buf1); nothing outstanding

  // ---- swiglu epilogue: even/odd col pairs = (h1,h3) ----
  #pragma unroll
  for (int mi = 0; mi < 8; mi++){
    #pragma unroll
    for (int ni = 0; ni < 4; ni++){
      #pragma unroll
      for (int r = 0; r < 4; r++){
        int row = wm * 128 + (mi >> 2) * 64 + (mi & 3) * 16 + quad * 4 + r;
        int col = cb + wn * 64 + (ni >> 1) * 32 + (ni & 1) * 16 + l16;
        float v = acc[mi][ni][r];
        float pv = __shfl_xor(v, 1, 64);
        int grow = rt + row;
        if (grow < cnt && (l16 & 1) == 0){
          float sl = v / (1.f + __expf(-v));
          size_t crow = (e < 8) ? (size_t)(off + grow) : (size_t)grow;
          Cb[crow * 1024 + (col >> 1)] = f2bf(sl * pv);
        }
      }
    }
  }
}

// ---- per-(b,h) V transpose: kv v-part [L,64] -> vt [64,L] ----
__global__ void vt_kernel(const u16* __restrict__ kv, u16* __restrict__ vt){
  __shared__ __align__(16) u16 t[64 * 72];
  int kt = blockIdx.x * 64, h = blockIdx.y, b = blockIdx.z;
  size_t bL = (size_t)b * Ll;
  int tid = threadIdx.x;
  int r = tid >> 2, c0 = (tid & 3) * 16;
  const u16* src = kv + (bL + kt + r) * 2048 + 1024 + h * 64 + c0;
  *(uint4*)&t[r * 72 + c0]     = *(const uint4*)(src);
  *(uint4*)&t[r * 72 + c0 + 8] = *(const uint4*)(src + 8);
  __syncthreads();
  int d = tid >> 2; int k0 = (tid & 3) * 16;
  u16 tmp[16];
  #pragma unroll
  for (int j = 0; j < 16; j++) tmp[j] = t[(k0 + j) * 72 + d];
  u16* dst = vt + ((size_t)(b * Hh + h) * 64 + d) * (size_t)Ll + kt + k0;
  *(uint4*)dst       = *(const uint4*)&tmp[0];
  *(uint4*)(dst + 8) = *(const uint4*)&tmp[8];
}

// ---- flash attention, S^T = K Q^T / O^T = V^T P; work-balanced: block x does
// q-bands {x, 31-x} (uniform 33 K-tiles/block). exp2-domain softmax (scale folded
// into q by the producing GEMM). Single-barrier double-buffered K/V pipeline with
// register prefetch (T14) + exact defer-max (T13, thr=0) + setprio (T5). ----
__launch_bounds__(256)
__global__ void attn_kernel(const u16* __restrict__ q, const u16* __restrict__ kv,
                            const u16* __restrict__ vt, u16* __restrict__ out){
  constexpr int LD = 72;
  __shared__ __align__(16) u16 Ks[2][64 * LD];
  __shared__ __align__(16) u16 Vs[2][64 * LD];
  __shared__ __align__(16) u16 Ps[64 * LD];
  int h = blockIdx.y, b = blockIdx.z;
  size_t bL = (size_t)b * Ll;
  int tid = threadIdx.x, w = tid >> 6, lane = tid & 63, quad = lane >> 4, l16 = lane & 15;
  int sr = tid >> 2, sc = (tid & 3) * 16;
  const u16* kbase = kv + (bL + sr) * 2048 + h * 64 + sc;
  const u16* vbase = vt + ((size_t)(b * Hh + h) * 64 + sr) * (size_t)Ll + sc;
  const f32x4 zf = {0.f, 0.f, 0.f, 0.f};

  #pragma unroll
  for (int pass = 0; pass < 2; pass++){
    int q0 = (pass ? (31 - (int)blockIdx.x) : (int)blockIdx.x) * 64;
    int qrow = q0 + w * 16 + l16;

    bf16x8 qf[2];
    #pragma unroll
    for (int ks = 0; ks < 2; ks++)
      qf[ks] = *(const bf16x8*)(q + (bL + qrow) * 1024 + h * 64 + ks * 32 + quad * 8);

    f32x4 oacc[4];
    #pragma unroll
    for (int dt = 0; dt < 4; dt++) oacc[dt] = zf;
    float mprev = -1e30f, lsum = 0.f;

    // prologue: stage tile 0 into buffer 0
    uint4 kr0 = *(const uint4*)(kbase);
    uint4 kr1 = *(const uint4*)(kbase + 8);
    uint4 vr0 = *(const uint4*)(vbase);
    uint4 vr1 = *(const uint4*)(vbase + 8);
    *(uint4*)&Ks[0][sr * LD + sc]     = kr0;
    *(uint4*)&Ks[0][sr * LD + sc + 8] = kr1;
    *(uint4*)&Vs[0][sr * LD + sc]     = vr0;
    *(uint4*)&Vs[0][sr * LD + sc + 8] = vr1;
    int cur = 0;
    __syncthreads();

    for (int kt = 0; kt <= q0; kt += 64){
      bool pfetch = (kt + 64 <= q0);
      // issue next tile's global loads early: latency hides under S+softmax+PV
      if (pfetch){
        const u16* kp = kbase + (size_t)(kt + 64) * 2048;
        kr0 = *(const uint4*)(kp);
        kr1 = *(const uint4*)(kp + 8);
        const u16* vp = vbase + kt + 64;
        vr0 = *(const uint4*)(vp);
        vr1 = *(const uint4*)(vp + 8);
      }
      const u16* ksp = Ks[cur];
      const u16* vsp = Vs[cur];

      f32x4 sacc[4];
      #pragma unroll
      for (int mt = 0; mt < 4; mt++) sacc[mt] = zf;
      __builtin_amdgcn_s_setprio(1);
      #pragma unroll
      for (int ks = 0; ks < 2; ks++){
        #pragma unroll
        for (int mt = 0; mt < 4; mt++){
          bf16x8 kf = *(const bf16x8*)&ksp[(mt * 16 + l16) * LD + ks * 32 + quad * 8];
          sacc[mt] = __builtin_amdgcn_mfma_f32_16x16x32_bf16(kf, qf[ks], sacc[mt], 0, 0, 0);
        }
      }
      __builtin_amdgcn_s_setprio(0);

      bool diag = (kt == q0);
      int lq = w * 16 + l16;
      float sv[16]; float mx = -1e30f;
      #pragma unroll
      for (int mt = 0; mt < 4; mt++){
        #pragma unroll
        for (int r = 0; r < 4; r++){
          float s = sacc[mt][r];                 // already log2-domain (q pre-scaled)
          if (diag && (mt * 16 + quad * 4 + r > lq)) s = -1e30f;
          sv[mt * 4 + r] = s;
          mx = fmaxf(mx, s);
        }
      }
      mx = fmaxf(mx, __shfl_xor(mx, 16, 64));
      mx = fmaxf(mx, __shfl_xor(mx, 32, 64));
      // exact defer-max: if no row's max grew, alpha == 1 exactly -> skip rescale
      if (!__all(mx <= mprev)){
        float mnew = fmaxf(mprev, mx);
        float alpha = exp2f(mprev - mnew);
        mprev = mnew;
        lsum *= alpha;
        #pragma unroll
        for (int dt = 0; dt < 4; dt++) oacc[dt] *= alpha;
      }
      float rs = 0.f;
      #pragma unroll
      for (int mt = 0; mt < 4; mt++){
        float p0 = exp2f(sv[mt * 4 + 0] - mprev);
        float p1 = exp2f(sv[mt * 4 + 1] - mprev);
        float p2 = exp2f(sv[mt * 4 + 2] - mprev);
        float p3 = exp2f(sv[mt * 4 + 3] - mprev);
        rs += p0 + p1 + p2 + p3;
        union { uint2 u; __hip_bfloat162 h2[2]; } pk;
        pk.h2[0] = __float22bfloat162_rn(make_float2(p0, p1));
        pk.h2[1] = __float22bfloat162_rn(make_float2(p2, p3));
        *(uint2*)&Ps[(w * 16 + l16) * LD + mt * 16 + quad * 4] = pk.u;
      }
      rs += __shfl_xor(rs, 16, 64);
      rs += __shfl_xor(rs, 32, 64);
      lsum += rs;

      __builtin_amdgcn_s_setprio(1);
      #pragma unroll
      for (int ks = 0; ks < 2; ks++){
        bf16x8 pfr = *(const bf16x8*)&Ps[(w * 16 + l16) * LD + ks * 32 + quad * 8];
        #pragma unroll
        for (int dt = 0; dt < 4; dt++){
          bf16x8 vf = *(const bf16x8*)&vsp[(dt * 16 + l16) * LD + ks * 32 + quad * 8];
          oacc[dt] = __builtin_amdgcn_mfma_f32_16x16x32_bf16(vf, pfr, oacc[dt], 0, 0, 0);
        }
      }
      __builtin_amdgcn_s_setprio(0);

      // write next tile into the alternate buffer (vmcnt wait lands here, hidden)
      if (pfetch){
        int nb = cur ^ 1;
        *(uint4*)&Ks[nb][sr * LD + sc]     = kr0;
        *(uint4*)&Ks[nb][sr * LD + sc + 8] = kr1;
        *(uint4*)&Vs[nb][sr * LD + sc]     = vr0;
        *(uint4*)&Vs[nb][sr * LD + sc + 8] = vr1;
        cur = nb;
      }
      __syncthreads();   // single barrier per tile
    }

    float inv = 1.f / lsum;
    #pragma unroll
    for (int dt = 0; dt < 4; dt++){
      union { uint2 u; __hip_bfloat162 h2[2]; } ov;
      ov.h2[0] = __float22bfloat162_rn(make_float2(oacc[dt][0] * inv, oacc[dt][1] * inv));
      ov.h2[1] = __float22bfloat162_rn(make_float2(oacc[dt][2] * inv, oacc[dt][3] * inv));
      *(uint2*)(out + (bL + qrow) * 1024 + h * 64 + dt * 16 + quad * 4) = ov.u;
    }
  }
}

// ---------------- host launch ----------------
extern "C" void kernel_launch(void* const* d_in, const int* in_sizes, int n_in,
                              void* d_out, int out_size, void* d_ws, size_t ws_size,
                              hipStream_t stream){
  const float* x     = (const float*)d_in[0];
  const float* ln1_w = (const float*)d_in[1];
  const float* q_w   = (const float*)d_in[2];
  const float* kvd_w = (const float*)d_in[3];
  const float* kvn_w = (const float*)d_in[4];
  const float* kvu_w = (const float*)d_in[5];
  const float* o_w   = (const float*)d_in[6];
  const float* ln2_w = (const float*)d_in[7];
  const float* gate_w= (const float*)d_in[8];
  const float* sh_w1 = (const float*)d_in[9];
  const float* sh_w2 = (const float*)d_in[10];
  const float* sh_w3 = (const float*)d_in[11];
  const float* re_w1 = (const float*)d_in[12];
  const float* re_w2 = (const float*)d_in[13];
  const float* re_w3 = (const float*)d_in[14];
  float* out = (float*)d_out;

  char* wp = (char*)d_ws;
  auto alloc = [&](size_t bytes)->char*{
    char* p = wp; wp += (bytes + 255) & ~(size_t)255; return p;
  };
  u16* qkvdT = (u16*)alloc((size_t)1280 * 1024 * 2);   // q rows 0..1023, kvd 1024..1279
  u16* kvuT  = (u16*)alloc((size_t)2048 * 256 * 2);
  u16* oT    = (u16*)alloc((size_t)1024 * 1024 * 2);
  u16* sh13T = (u16*)alloc((size_t)2048 * 1024 * 2);   // interleaved w1/w3 rows
  u16* sh2T  = (u16*)alloc((size_t)1024 * 1024 * 2);
  u16* re13T = (u16*)alloc((size_t)8 * 2048 * 1024 * 2); // interleaved per expert
  u16* re2T  = (u16*)alloc((size_t)8 * 1024 * 1024 * 2);
  u16* xn    = (u16*)alloc((size_t)Tt * 1024 * 2);     // xn, later hn
  u16* qbuf  = (u16*)alloc((size_t)Tt * 1024 * 2);
  float* latpre = (float*)alloc((size_t)Tt * 256 * 4); // fp32 (routing-critical)
  u16* lat   = (u16*)alloc((size_t)Tt * 256 * 2);
  u16* kvbuf = (u16*)alloc((size_t)Tt * 2048 * 2);     // kv, later shared g [T,1024]
  u16* attnb = (u16*)alloc((size_t)Tt * 1024 * 2);
  float* hbuf = (float*)alloc((size_t)Tt * 1024 * 4);
  u16* vtb   = (u16*)alloc((size_t)Bb * Hh * 64 * Ll * 2);
  u16* gr    = (u16*)alloc((size_t)Tt * 2 * 1024 * 2); // routed g [2T,1024]
  int* counts = (int*)alloc(32);
  int* cur    = (int*)alloc(32);
  int* topi   = (int*)alloc((size_t)Tt * 2 * 4);
  float* topw = (float*)alloc((size_t)Tt * 2 * 4);
  int* entries= (int*)alloc((size_t)Tt * 2 * 4);
  float* ewt  = (float*)alloc((size_t)Tt * 2 * 4);
  (void)ws_size; (void)n_in; (void)in_sizes; (void)out_size;

  hipMemsetAsync(counts, 0, 32, stream);
  hipMemsetAsync(cur, 0, 32, stream);

  dim3 tb(32, 8);
  transpose5<<<dim3(32, 32, 5), tb, 0, stream>>>(q_w, o_w, sh_w1, sh_w3, sh_w2,
                                                 qkvdT, oT, sh13T, sh2T);
  transpose_conv<<<dim3(8, 32, 1), tb, 0, stream>>>(kvd_w, qkvdT, 1024, 256, 1024);
  transpose_conv<<<dim3(64, 8, 1), tb, 0, stream>>>(kvu_w, kvuT, 256, 2048, 0);
  transposeEx<<<dim3(32, 32, 24), tb, 0, stream>>>(re_w1, re_w3, re_w2, re13T, re2T);

  // xn = rmsnorm(x, ln1_w)
  rmsnorm_kernel<1024><<<Tt, 256, 0, stream>>>(x, ln1_w, xn);

  // [q(bf16, pre-scaled by QSCALE) | latent_pre(fp32)] = xn @ [q_w | kvd_w]
  gemm_bt<64,0,5><<<dim3(10, 64), 256, 0, stream>>>(xn, qkvdT, qbuf, nullptr,
      Tt, 1280, 1024, 1024, 1024, nullptr, nullptr, nullptr, latpre);
  rmsnorm_kernel<256><<<Tt, 256, 0, stream>>>(latpre, kvn_w, lat);
  // kv = latent @ kvu_w
  gemm_bt<128,0,0><<<dim3(16, 32), 256, 0, stream>>>(lat, kvuT, kvbuf, nullptr,
      Tt, 2048, 256, 256, 2048, nullptr, nullptr, nullptr, nullptr);
  // attention
  vt_kernel<<<dim3(32, 16, 2), 256, 0, stream>>>(kvbuf, vtb);
  attn_kernel<<<dim3(16, 16, 2), 256, 0, stream>>>(qbuf, kvbuf, vtb, attnb);
  // h = x + attn_out @ o_w
  gemm_bt<64,0,1><<<dim3(8, 64), 256, 0, stream>>>(attnb, oT, hbuf, x,
      Tt, 1024, 1024, 1024, 1024, nullptr, nullptr, nullptr, nullptr);
  // router (also writes hn into xn)
  router_kernel<<<Tt, 256, 0, stream>>>(hbuf, ln2_w, gate_w, out + (size_t)Tt * Dd,
                                        topi, topw, xn);
  hist_kernel<<<16, 256, 0, stream>>>(topi, counts);
  bucket_kernel<<<16, 256, 0, stream>>>(topi, topw, counts, cur, entries, ewt);

  // shared + routed up-projections (swiglu), one grouped 8-phase launch:
  //   z=0..7: gr[entry-space] = swiglu(gather(hn) @ re13[e])
  //   z=8:    kvbuf = swiglu(hn @ sh13)
  gemm256_up<<<dim3(8, 16, 9), 512, 0, stream>>>(xn, sh13T, re13T, kvbuf, gr,
                                                 entries, counts);

  // out = h + g @ w2  (shared down)
  gemm_bt<64,0,1><<<dim3(8, 64), 256, 0, stream>>>(kvbuf, sh2T, out, hbuf,
      Tt, 1024, 1024, 1024, 1024, nullptr, nullptr, nullptr, nullptr);
  // routed down: out += w * (gr @ w2e)
  gemm_bt<128,2,4><<<dim3(8, 32, 8), 256, 0, stream>>>(gr, re2T, nullptr, nullptr,
      Tt, 1024, 1024, 1024, 1024, entries, ewt, counts, out);
}

// Round 4
// 547.132 us; speedup vs baseline: 1.0073x; 1.0073x over previous
//
#include <hip/hip_runtime.h>
#include <hip/hip_bf16.h>
#include <cstdint>
#include <cstddef>

typedef unsigned short u16;
typedef unsigned int u32;
typedef __attribute__((ext_vector_type(8))) short bf16x8;
typedef __attribute__((ext_vector_type(4))) float f32x4;

static constexpr int Bb = 2, Ll = 2048, Dd = 1024, Hh = 16, Rr = 256, Ee = 8, Ff = 1024;
static constexpr int Tt = Bb * Ll;   // 4096 tokens
// softmax scale folded into q at the GEMM epilogue: 0.125 * log2(e)
static constexpr float QSCALE = 0.18033688011112042f;

__device__ __forceinline__ u16 f2bf(float f){
  union { float f; u32 u; } v; v.f = f;
  u32 u = v.u;
  u32 r = u + 0x7FFFu + ((u >> 16) & 1u);
  return (u16)(r >> 16);
}
__device__ __forceinline__ float bf2f(u16 b){
  union { u32 u; float f; } v; v.u = ((u32)b) << 16; return v.f;
}

// async global->LDS, 16B per lane. LDS dest wave-uniform base + lane*16. Full exec only.
#define GLDS(gp, lp) __builtin_amdgcn_global_load_lds( \
    (const __attribute__((address_space(1))) unsigned int*)(gp), \
    (__attribute__((address_space(3))) unsigned int*)(lp), 16, 0, 0)

// ---- batched transpose+convert for the five 1024x1024 non-expert weights ----
__global__ void transpose5(const float* __restrict__ q_w, const float* __restrict__ o_w,
                           const float* __restrict__ w1, const float* __restrict__ w3,
                           const float* __restrict__ w2,
                           u16* __restrict__ qkvdT, u16* __restrict__ oT,
                           u16* __restrict__ sh13T, u16* __restrict__ sh2T){
  const float* s; u16* d; int off, str;
  switch (blockIdx.z){
    case 0: s = q_w; d = qkvdT; off = 0; str = 1; break;
    case 1: s = o_w; d = oT;    off = 0; str = 1; break;
    case 2: s = w1;  d = sh13T; off = 0; str = 2; break;   // interleaved w1|w3
    case 3: s = w3;  d = sh13T; off = 1; str = 2; break;
    default: s = w2; d = sh2T;  off = 0; str = 1; break;
  }
  __shared__ float tile[32][33];
  int bx = blockIdx.x * 32, by = blockIdx.y * 32;
  int tx = threadIdx.x, ty = threadIdx.y;
  #pragma unroll
  for (int i = ty; i < 32; i += 8) tile[i][tx] = s[(size_t)(by + i) * 1024 + bx + tx];
  __syncthreads();
  #pragma unroll
  for (int i = ty; i < 32; i += 8)
    d[(size_t)(off + (bx + i) * str) * 1024 + by + tx] = f2bf(tile[tx][i]);
}

// ---- batched transpose+convert for the 24 expert weights ----
__global__ void transposeEx(const float* __restrict__ re_w1, const float* __restrict__ re_w3,
                            const float* __restrict__ re_w2,
                            u16* __restrict__ re13T, u16* __restrict__ re2T){
  int z = blockIdx.z, which = z >> 3, e = z & 7;
  const float* s; u16* d; int off, str;
  size_t eo = (size_t)e * 1024 * 1024;
  if (which == 0){ s = re_w1 + eo; d = re13T + (size_t)e * 2048 * 1024; off = 0; str = 2; }
  else if (which == 1){ s = re_w3 + eo; d = re13T + (size_t)e * 2048 * 1024; off = 1; str = 2; }
  else { s = re_w2 + eo; d = re2T + (size_t)e * 1024 * 1024; off = 0; str = 1; }
  __shared__ float tile[32][33];
  int bx = blockIdx.x * 32, by = blockIdx.y * 32;
  int tx = threadIdx.x, ty = threadIdx.y;
  #pragma unroll
  for (int i = ty; i < 32; i += 8) tile[i][tx] = s[(size_t)(by + i) * 1024 + bx + tx];
  __syncthreads();
  #pragma unroll
  for (int i = ty; i < 32; i += 8)
    d[(size_t)(off + (bx + i) * str) * 1024 + by + tx] = f2bf(tile[tx][i]);
}

// ---- generic transpose (kvd: K=1024,N=256 ; kvu: K=256,N=2048) ----
__global__ void transpose_conv(const float* __restrict__ src, u16* __restrict__ dst,
                               int K, int N, int dstOff){
  __shared__ float tile[32][33];
  int bx = blockIdx.x * 32, by = blockIdx.y * 32;
  int tx = threadIdx.x, ty = threadIdx.y;
  #pragma unroll
  for (int i = ty; i < 32; i += 8) tile[i][tx] = src[(size_t)(by + i) * N + bx + tx];
  __syncthreads();
  #pragma unroll
  for (int i = ty; i < 32; i += 8)
    dst[(size_t)(dstOff + bx + i) * K + by + tx] = f2bf(tile[tx][i]);
}

// ---- rmsnorm: fp32 in -> bf16 out ----
template<int DIM>
__global__ void rmsnorm_kernel(const float* __restrict__ x, const float* __restrict__ w,
                               u16* __restrict__ out){
  int t = blockIdx.x;
  const float* xr = x + (size_t)t * DIM;
  u16* orow = out + (size_t)t * DIM;
  int tid = threadIdx.x;
  constexpr int NT = 256;
  constexpr int PER = DIM / NT > 0 ? DIM / NT : 1;
  float vals[PER];
  float ss = 0.f;
  #pragma unroll
  for (int i = 0; i < PER; i++){
    int d = tid + i * NT;
    float v = (d < DIM) ? xr[d] : 0.f;
    vals[i] = v; ss += v * v;
  }
  __shared__ float red[4];
  for (int m = 32; m; m >>= 1) ss += __shfl_xor(ss, m, 64);
  if ((tid & 63) == 0) red[tid >> 6] = ss;
  __syncthreads();
  float tot = red[0] + red[1] + red[2] + red[3];
  float rn = rsqrtf(tot / DIM + 1e-6f);
  #pragma unroll
  for (int i = 0; i < PER; i++){
    int d = tid + i * NT;
    if (d < DIM) orow[d] = f2bf(vals[i] * rn * w[d]);
  }
}

// ---- router: fp32 rmsnorm(h)@gate, softmax, top2; ALSO writes hn (bf16) ----
__global__ void router_kernel(const float* __restrict__ h, const float* __restrict__ ln2w,
                              const float* __restrict__ gate,
                              float* __restrict__ probs_out,
                              int* __restrict__ topi, float* __restrict__ topw,
                              u16* __restrict__ hn){
  int t = blockIdx.x; int tid = threadIdx.x;
  const float* hr = h + (size_t)t * Dd;
  float v[4]; float ss = 0.f;
  #pragma unroll
  for (int i = 0; i < 4; i++){ float x = hr[tid + i * 256]; v[i] = x; ss += x * x; }
  __shared__ float red[4];
  for (int m = 32; m; m >>= 1) ss += __shfl_xor(ss, m, 64);
  if ((tid & 63) == 0) red[tid >> 6] = ss;
  __syncthreads();
  float rn = rsqrtf((red[0] + red[1] + red[2] + red[3]) / Dd + 1e-6f);
  float p[8];
  #pragma unroll
  for (int e = 0; e < 8; e++) p[e] = 0.f;
  #pragma unroll
  for (int i = 0; i < 4; i++){
    int d = tid + i * 256;
    float hv = v[i] * rn * ln2w[d];
    hn[(size_t)t * Dd + d] = f2bf(hv);
    const float* g = gate + (size_t)d * 8;
    #pragma unroll
    for (int e = 0; e < 8; e++) p[e] += hv * g[e];
  }
  #pragma unroll
  for (int e = 0; e < 8; e++){
    float x = p[e];
    for (int m = 32; m; m >>= 1) x += __shfl_xor(x, m, 64);
    p[e] = x;
  }
  __shared__ float pe[4][8];
  if ((tid & 63) == 0){ for (int e = 0; e < 8; e++) pe[tid >> 6][e] = p[e]; }
  __syncthreads();
  if (tid == 0){
    float lg[8];
    for (int e = 0; e < 8; e++) lg[e] = pe[0][e] + pe[1][e] + pe[2][e] + pe[3][e];
    float mx = lg[0];
    for (int e = 1; e < 8; e++) mx = fmaxf(mx, lg[e]);
    float pr[8]; float s = 0.f;
    for (int e = 0; e < 8; e++){ pr[e] = __expf(lg[e] - mx); s += pr[e]; }
    float inv = 1.f / s;
    for (int e = 0; e < 8; e++) probs_out[(size_t)t * 8 + e] = pr[e] * inv;
    int i0 = 0;
    for (int e = 1; e < 8; e++) if (pr[e] > pr[i0]) i0 = e;
    int i1 = -1;
    for (int e = 0; e < 8; e++){ if (e == i0) continue; if (i1 < 0 || pr[e] > pr[i1]) i1 = e; }
    float w0 = pr[i0], w1 = pr[i1]; float wn = 1.f / (w0 + w1);
    topi[t * 2] = i0; topi[t * 2 + 1] = i1;
    topw[t * 2] = w0 * wn; topw[t * 2 + 1] = w1 * wn;
  }
}

// ---- histogram of topi -> counts (LDS-aggregated) ----
__global__ void hist_kernel(const int* __restrict__ topi, int* __restrict__ counts){
  __shared__ int h[8];
  int tid = threadIdx.x;
  if (tid < 8) h[tid] = 0;
  __syncthreads();
  int base = blockIdx.x * 512;
  for (int i = tid; i < 512; i += 256) atomicAdd(&h[topi[base + i]], 1);
  __syncthreads();
  if (tid < 8) atomicAdd(&counts[tid], h[tid]);
}

// ---- bucket: LDS histogram + chunk reservation; offsets computed from counts ----
__global__ void bucket_kernel(const int* __restrict__ topi, const float* __restrict__ topw,
                              const int* __restrict__ counts, int* __restrict__ cur,
                              int* __restrict__ entries, float* __restrict__ ew){
  __shared__ int lh[8], lbase[8], lcur[8], loffs[8];
  int tid = threadIdx.x;
  if (tid < 8) lh[tid] = 0;
  __syncthreads();
  int t = blockIdx.x * 256 + tid;
  int e0 = topi[t * 2], e1 = topi[t * 2 + 1];
  atomicAdd(&lh[e0], 1); atomicAdd(&lh[e1], 1);
  __syncthreads();
  if (tid == 0){
    int c = 0;
    for (int e = 0; e < 8; e++){ loffs[e] = c; c += counts[e]; }
  }
  if (tid < 8){ lbase[tid] = atomicAdd(&cur[tid], lh[tid]); lcur[tid] = 0; }
  __syncthreads();
  int p0 = atomicAdd(&lcur[e0], 1);
  int pos0 = loffs[e0] + lbase[e0] + p0;
  entries[pos0] = t; ew[pos0] = topw[t * 2];
  int p1 = atomicAdd(&lcur[e1], 1);
  int pos1 = loffs[e1] + lbase[e1] + p1;
  entries[pos1] = t; ew[pos1] = topw[t * 2 + 1];
}

// ---- bf16 GEMM: C[M,N] = A[M,K] @ Bt[N,K]^T ; m97 structure, tile TM x 128, BK=32 ----
// ROWMODE: 0 dense; 1 gather rows via entries; 2 dense-in-entry-space (A row = off+r)
// MODE: 0 bf16 C; 1 f32 C = acc + res; 4 atomicAdd(out[token], w*acc);
//       5 split: col<1024 -> bf16 C scaled by QSCALE (q for attn, log2-domain softmax);
//                col>=1024 -> fp32 outAt (latent-pre, routing-critical)
//       6 swiglu: interleaved even/odd cols = (h1,h3); write silu(h1)*h3 bf16 at col>>1
template<int TM, int ROWMODE, int MODE>
__launch_bounds__(256)
__global__ void gemm_bt(const u16* __restrict__ A, const u16* __restrict__ Bt,
                        void* __restrict__ C, const float* __restrict__ res,
                        int M, int N, int K, int lda, int ldc,
                        const int* __restrict__ entries, const float* __restrict__ ew,
                        const int* __restrict__ counts,
                        float* __restrict__ outAt){
  constexpr int MTC = TM / 32;
  __shared__ __align__(16) u16 As[TM * 32];
  __shared__ __align__(16) u16 Bs[128 * 32];
  __shared__ int els[TM];
  __shared__ float ewl[TM];

  int e = (ROWMODE ? blockIdx.z : 0);
  const u16* Bte = Bt + (size_t)e * N * K;
  int cnt, off;
  if (ROWMODE == 0){ cnt = M; off = 0; }
  else {
    cnt = counts[e];
    off = 0;
    for (int i = 0; i < e; i++) off += counts[i];
  }
  int rt = blockIdx.y * TM;
  if (rt >= cnt) return;
  int cb = blockIdx.x * 128;
  int tid = threadIdx.x;

  if (ROWMODE >= 1){
    if (tid < TM){
      int r = rt + tid;
      els[tid] = (r < cnt) ? entries[off + r] : 0;
      ewl[tid] = (MODE == 4 && r < cnt) ? ew[off + r] : 0.f;
    }
    __syncthreads();
  }

  int sr = tid >> 2;
  int skc = (tid & 3) * 8;
  int rr0 = rt + sr, rr1 = rt + sr + 64;
  size_t ar0 = 0, ar1 = 0;
  if (ROWMODE == 0){ ar0 = (size_t)rr0; ar1 = (size_t)rr1; }
  else if (ROWMODE == 1){ ar0 = (size_t)els[sr];
                          ar1 = (TM == 128) ? (size_t)els[sr + 64] : 0; }
  else {
    int c0 = rr0 < cnt ? rr0 : (cnt - 1);
    int c1 = rr1 < cnt ? rr1 : (cnt - 1);
    ar0 = (size_t)off + c0; ar1 = (size_t)off + c1;
  }
  const u16* pa0 = A + ar0 * lda + skc;
  const u16* pa1 = A + ar1 * lda + skc;
  const u16* pb0 = Bte + (size_t)(cb + sr) * K + skc;
  const u16* pb1 = Bte + (size_t)(cb + sr + 64) * K + skc;
  u16* lA0 = &As[tid * 8];
  u16* lA1 = &As[(TM == 128 ? 2048 : 0) + tid * 8];
  u16* lB0 = &Bs[tid * 8];
  u16* lB1 = &Bs[2048 + tid * 8];

  int w = tid >> 6, lane = tid & 63;
  int wm = w >> 1, wn = w & 1;
  int quad = lane >> 4, l16 = lane & 15;

  f32x4 acc[MTC][4];
  const f32x4 zf = {0.f, 0.f, 0.f, 0.f};
  #pragma unroll
  for (int i = 0; i < MTC; i++)
    #pragma unroll
    for (int j = 0; j < 4; j++) acc[i][j] = zf;

  for (int k0 = 0; k0 < K; k0 += 32){
    __syncthreads();
    GLDS(pa0 + k0, lA0);
    if (TM == 128) GLDS(pa1 + k0, lA1);
    GLDS(pb0 + k0, lB0);
    GLDS(pb1 + k0, lB1);
    __syncthreads();
    bf16x8 af[MTC], bfr[4];
    #pragma unroll
    for (int mt = 0; mt < MTC; mt++)
      af[mt] = *(const bf16x8*)&As[(wm * (TM / 2) + mt * 16 + l16) * 32 + quad * 8];
    #pragma unroll
    for (int nt = 0; nt < 4; nt++)
      bfr[nt] = *(const bf16x8*)&Bs[(wn * 64 + nt * 16 + l16) * 32 + quad * 8];
    #pragma unroll
    for (int mt = 0; mt < MTC; mt++)
      #pragma unroll
      for (int nt = 0; nt < 4; nt++)
        acc[mt][nt] = __builtin_amdgcn_mfma_f32_16x16x32_bf16(af[mt], bfr[nt], acc[mt][nt], 0, 0, 0);
  }

  #pragma unroll
  for (int mt = 0; mt < MTC; mt++){
    #pragma unroll
    for (int nt = 0; nt < 4; nt++){
      #pragma unroll
      for (int r = 0; r < 4; r++){
        int row = wm * (TM / 2) + mt * 16 + quad * 4 + r;
        int col = cb + wn * 64 + nt * 16 + l16;
        int rr = rt + row;
        float v = acc[mt][nt][r];
        if (MODE == 6){
          float pv = __shfl_xor(v, 1, 64);      // partner col (all lanes execute)
          if (rr < cnt && (l16 & 1) == 0){
            float sl = v / (1.f + __expf(-v));
            size_t crow = (size_t)((ROWMODE == 1) ? (off + rr) : rr);
            ((u16*)C)[crow * ldc + (col >> 1)] = f2bf(sl * pv);
          }
          continue;
        }
        if (rr >= cnt) continue;
        if (MODE == 0){
          size_t ci = (size_t)((ROWMODE == 1) ? (off + rr) : rr) * ldc + col;
          ((u16*)C)[ci] = f2bf(v);
        } else if (MODE == 1){
          size_t ci = (size_t)rr * ldc + col;
          ((float*)C)[ci] = v + res[ci];
        } else if (MODE == 5){
          if (col < 1024) ((u16*)C)[(size_t)rr * 1024 + col] = f2bf(v * QSCALE);
          else            outAt[(size_t)rr * 256 + (col - 1024)] = v;
        } else {
          int tok = els[row];
          atomicAdd(&outAt[(size_t)tok * ldc + col], ewl[row] * v);
        }
      }
    }
  }
}

// ======== 256x256 grouped swiglu up-projection (T2+T4+T5, relaxed barriers) ====
// z = expert: 0..7 routed (A rows gathered via entries, C = gr in entry space),
//             8 = shared (identity rows, C = shg).  N=2048 interleaved w1|w3,
//             K=1024, BK=64, 512 threads (2Mx4N waves), 128 KiB dbuf LDS.
// LDS XOR-swizzle source-side + read-side -> conflict-free ds_read_b128.
// Schedule: 2 barriers per K-tile only. All 24 ds_reads issued up front, then
// 64 MFMAs -- waves free-run, so one wave's LDS reads overlap another's MFMAs
// (no lockstep read-burst/MFMA-burst serialization). Barrier 1 = write-after-
// read guard (sched_barrier(0) pins read consumption above it); stage tile t+2
// into the just-freed buffer; counted vmcnt(8) + barrier 2 = read-after-write.
#define RBAR() __builtin_amdgcn_s_barrier()
#define SBAR0() __builtin_amdgcn_sched_barrier(0)
#define VMCNT8() do{ asm volatile("s_waitcnt vmcnt(8)" ::: "memory"); \
                     __builtin_amdgcn_sched_barrier(0); }while(0)
#define VMCNT0() do{ asm volatile("s_waitcnt vmcnt(0)" ::: "memory"); \
                     __builtin_amdgcn_sched_barrier(0); }while(0)
#define MMQ(MQ, NQ, FA, FB) do{ \
  _Pragma("unroll") \
  for (int m4_ = 0; m4_ < 4; m4_++){ \
    _Pragma("unroll") \
    for (int n2_ = 0; n2_ < 2; n2_++){ \
      acc[(MQ)*4+m4_][(NQ)*2+n2_] = __builtin_amdgcn_mfma_f32_16x16x32_bf16(FA[m4_][0], FB[n2_][0], acc[(MQ)*4+m4_][(NQ)*2+n2_], 0, 0, 0); \
      acc[(MQ)*4+m4_][(NQ)*2+n2_] = __builtin_amdgcn_mfma_f32_16x16x32_bf16(FA[m4_][1], FB[n2_][1], acc[(MQ)*4+m4_][(NQ)*2+n2_], 0, 0, 0); \
    } \
  } }while(0)
#define RDA(DST, BB, MQ) do{ \
  _Pragma("unroll") \
  for (int m4_ = 0; m4_ < 4; m4_++){ \
    const char* p_ = (const char*)(&As[BB][0]) + (size_t)(wm*128 + (MQ)*64 + m4_*16 + l16)*128; \
    DST[m4_][0] = *(const bf16x8*)(p_ + offk0); \
    DST[m4_][1] = *(const bf16x8*)(p_ + offk1); \
  } }while(0)
#define RDB(DST, BB, NQ) do{ \
  _Pragma("unroll") \
  for (int n2_ = 0; n2_ < 2; n2_++){ \
    const char* p_ = (const char*)(&Bs[BB][0]) + (size_t)(wn*64 + (NQ)*32 + n2_*16 + l16)*128; \
    DST[n2_][0] = *(const bf16x8*)(p_ + offk0); \
    DST[n2_][1] = *(const bf16x8*)(p_ + offk1); \
  } }while(0)
#define STGA(SB, H, KT) do{ \
  GLDS(gA[(H)*2+0] + (size_t)(KT)*64, &As[SB][((H)*128 +  0)*64] + (size_t)tid*8); \
  GLDS(gA[(H)*2+1] + (size_t)(KT)*64, &As[SB][((H)*128 + 64)*64] + (size_t)tid*8); }while(0)
#define STGB(SB, H, KT) do{ \
  GLDS(gB[(H)*2+0] + (size_t)(KT)*64, &Bs[SB][((H)*128 +  0)*64] + (size_t)tid*8); \
  GLDS(gB[(H)*2+1] + (size_t)(KT)*64, &Bs[SB][((H)*128 + 64)*64] + (size_t)tid*8); }while(0)

__launch_bounds__(512, 2)
__global__ void gemm256_up(const u16* __restrict__ A,
                           const u16* __restrict__ sh13, const u16* __restrict__ re13,
                           u16* __restrict__ shg, u16* __restrict__ gr,
                           const int* __restrict__ entries, const int* __restrict__ counts){
  __shared__ __align__(16) u16 As[2][256 * 64];
  __shared__ __align__(16) u16 Bs[2][256 * 64];

  int e = blockIdx.z;
  int cnt, off = 0;
  if (e < 8){
    cnt = counts[e];
    for (int i = 0; i < e; i++) off += counts[i];
  } else cnt = Tt;
  int rt = blockIdx.y * 256;
  if (rt >= cnt) return;
  int cb = blockIdx.x * 256;
  const u16* Bte = (e < 8) ? (re13 + (size_t)e * 2048 * 1024) : sh13;
  u16* Cb = (e < 8) ? gr : shg;

  int tid = threadIdx.x;
  int w = tid >> 6, lane = tid & 63, quad = lane >> 4, l16 = lane & 15;
  int wm = w >> 2, wn = w & 3;                 // 2 x 4 wave grid
  int swz = (l16 & 7) << 4;                    // per-lane XOR (bytes)
  int offk0 = (quad * 16) ^ swz;               // ks=0 byte col (swizzled)
  int offk1 = (64 + quad * 16) ^ swz;          // ks=1

  // staging: thread covers row (i*64 + tid/8), 16B chunk (tid&7), src pre-swizzled
  int trow = tid >> 3;
  int sk = ((((tid & 7) << 4) ^ ((trow & 7) << 4)) >> 1);   // bf16 elems
  const u16* gA[4]; const u16* gB[4];
  #pragma unroll
  for (int i = 0; i < 4; i++){
    int r = i * 64 + trow;                     // tile row 0..255
    int garow;
    if (e < 8){
      int idx = rt + r; if (idx >= cnt) idx = cnt - 1;
      garow = entries[off + idx];
    } else garow = rt + r;
    gA[i] = A + (size_t)garow * 1024 + sk;
    gB[i] = Bte + (size_t)(cb + r) * 1024 + sk;
  }

  f32x4 acc[8][4];
  const f32x4 zf = {0.f, 0.f, 0.f, 0.f};
  #pragma unroll
  for (int i = 0; i < 8; i++)
    #pragma unroll
    for (int j = 0; j < 4; j++) acc[i][j] = zf;

  // K-tile body, 2 barriers/tile:
  //   reads (all 24) + 64 MFMAs free-run; sched_barrier pins them above RBAR#1
  //   RBAR#1: every wave done reading buf[b] -> safe to overwrite
  //   stage tile t2 -> buf[b]; counted vmcnt (tile t+1 done, t+2 in flight)
  //   RBAR#2: tile t+1's buffer ready for all waves
  auto tile = [&](int b, int t2, int mode){   // mode: 0 stage+vmcnt8, 1 vmcnt0, 2 last
    bf16x8 fa0[4][2], fa1[4][2], fb0[2][2], fb1[2][2];
    RDA(fa0, b, 0); RDB(fb0, b, 0);
    RDB(fb1, b, 1); RDA(fa1, b, 1);
    __builtin_amdgcn_s_setprio(1);
    MMQ(0, 0, fa0, fb0); MMQ(0, 1, fa0, fb1);
    MMQ(1, 0, fa1, fb0); MMQ(1, 1, fa1, fb1);
    __builtin_amdgcn_s_setprio(0);
    if (mode == 2) return;
    SBAR0();
    RBAR();                      // write-after-read guard
    if (mode == 0){
      STGB(b, 0, t2); STGB(b, 1, t2); STGA(b, 0, t2); STGA(b, 1, t2);
      VMCNT8();
    } else {
      VMCNT0();
    }
    RBAR();                      // read-after-write guard
    SBAR0();
  };

  // prologue: stage tile 0 -> buf0, tile 1 -> buf1; wait only for tile 0
  STGB(0, 0, 0); STGB(0, 1, 0); STGA(0, 0, 0); STGA(0, 1, 0);
  STGB(1, 0, 1); STGB(1, 1, 1); STGA(1, 0, 1); STGA(1, 1, 1);
  VMCNT8();            // drain tile0's 8 loads; tile1's 8 stay in flight
  RBAR();

  for (int t = 0; t < 14; ++t) tile(t & 1, t + 2, 0);
  tile(0, 0, 1);       // t = 14 (buf0); drain tile 15's loads
  tile(1, 0, 2);       // t = 15 (buf1); nothing outstanding

  // ---- swiglu epilogue: even/odd col pairs = (h1,h3) ----
  #pragma unroll
  for (int mi = 0; mi < 8; mi++){
    #pragma unroll
    for (int ni = 0; ni < 4; ni++){
      #pragma unroll
      for (int r = 0; r < 4; r++){
        int row = wm * 128 + (mi >> 2) * 64 + (mi & 3) * 16 + quad * 4 + r;
        int col = cb + wn * 64 + (ni >> 1) * 32 + (ni & 1) * 16 + l16;
        float v = acc[mi][ni][r];
        float pv = __shfl_xor(v, 1, 64);
        int grow = rt + row;
        if (grow < cnt && (l16 & 1) == 0){
          float sl = v / (1.f + __expf(-v));
          size_t crow = (e < 8) ? (size_t)(off + grow) : (size_t)grow;
          Cb[crow * 1024 + (col >> 1)] = f2bf(sl * pv);
        }
      }
    }
  }
}

// ---- per-(b,h) V transpose: kv v-part [L,64] -> vt [64,L] ----
__global__ void vt_kernel(const u16* __restrict__ kv, u16* __restrict__ vt){
  __shared__ __align__(16) u16 t[64 * 72];
  int kt = blockIdx.x * 64, h = blockIdx.y, b = blockIdx.z;
  size_t bL = (size_t)b * Ll;
  int tid = threadIdx.x;
  int r = tid >> 2, c0 = (tid & 3) * 16;
  const u16* src = kv + (bL + kt + r) * 2048 + 1024 + h * 64 + c0;
  *(uint4*)&t[r * 72 + c0]     = *(const uint4*)(src);
  *(uint4*)&t[r * 72 + c0 + 8] = *(const uint4*)(src + 8);
  __syncthreads();
  int d = tid >> 2; int k0 = (tid & 3) * 16;
  u16 tmp[16];
  #pragma unroll
  for (int j = 0; j < 16; j++) tmp[j] = t[(k0 + j) * 72 + d];
  u16* dst = vt + ((size_t)(b * Hh + h) * 64 + d) * (size_t)Ll + kt + k0;
  *(uint4*)dst       = *(const uint4*)&tmp[0];
  *(uint4*)(dst + 8) = *(const uint4*)&tmp[8];
}

// ---- flash attention, S^T = K Q^T / O^T = V^T P; work-balanced: block x does
// q-bands {x, 31-x} (uniform 33 K-tiles/block). exp2-domain softmax (scale folded
// into q by the producing GEMM). Single-barrier double-buffered K/V pipeline with
// register prefetch (T14) + exact defer-max (T13, thr=0) + setprio (T5). ----
__launch_bounds__(256)
__global__ void attn_kernel(const u16* __restrict__ q, const u16* __restrict__ kv,
                            const u16* __restrict__ vt, u16* __restrict__ out){
  constexpr int LD = 72;
  __shared__ __align__(16) u16 Ks[2][64 * LD];
  __shared__ __align__(16) u16 Vs[2][64 * LD];
  __shared__ __align__(16) u16 Ps[64 * LD];
  int h = blockIdx.y, b = blockIdx.z;
  size_t bL = (size_t)b * Ll;
  int tid = threadIdx.x, w = tid >> 6, lane = tid & 63, quad = lane >> 4, l16 = lane & 15;
  int sr = tid >> 2, sc = (tid & 3) * 16;
  const u16* kbase = kv + (bL + sr) * 2048 + h * 64 + sc;
  const u16* vbase = vt + ((size_t)(b * Hh + h) * 64 + sr) * (size_t)Ll + sc;
  const f32x4 zf = {0.f, 0.f, 0.f, 0.f};

  #pragma unroll
  for (int pass = 0; pass < 2; pass++){
    int q0 = (pass ? (31 - (int)blockIdx.x) : (int)blockIdx.x) * 64;
    int qrow = q0 + w * 16 + l16;

    bf16x8 qf[2];
    #pragma unroll
    for (int ks = 0; ks < 2; ks++)
      qf[ks] = *(const bf16x8*)(q + (bL + qrow) * 1024 + h * 64 + ks * 32 + quad * 8);

    f32x4 oacc[4];
    #pragma unroll
    for (int dt = 0; dt < 4; dt++) oacc[dt] = zf;
    float mprev = -1e30f, lsum = 0.f;

    // prologue: stage tile 0 into buffer 0
    uint4 kr0 = *(const uint4*)(kbase);
    uint4 kr1 = *(const uint4*)(kbase + 8);
    uint4 vr0 = *(const uint4*)(vbase);
    uint4 vr1 = *(const uint4*)(vbase + 8);
    *(uint4*)&Ks[0][sr * LD + sc]     = kr0;
    *(uint4*)&Ks[0][sr * LD + sc + 8] = kr1;
    *(uint4*)&Vs[0][sr * LD + sc]     = vr0;
    *(uint4*)&Vs[0][sr * LD + sc + 8] = vr1;
    int cur = 0;
    __syncthreads();

    for (int kt = 0; kt <= q0; kt += 64){
      bool pfetch = (kt + 64 <= q0);
      // issue next tile's global loads early: latency hides under S+softmax+PV
      if (pfetch){
        const u16* kp = kbase + (size_t)(kt + 64) * 2048;
        kr0 = *(const uint4*)(kp);
        kr1 = *(const uint4*)(kp + 8);
        const u16* vp = vbase + kt + 64;
        vr0 = *(const uint4*)(vp);
        vr1 = *(const uint4*)(vp + 8);
      }
      const u16* ksp = Ks[cur];
      const u16* vsp = Vs[cur];

      f32x4 sacc[4];
      #pragma unroll
      for (int mt = 0; mt < 4; mt++) sacc[mt] = zf;
      __builtin_amdgcn_s_setprio(1);
      #pragma unroll
      for (int ks = 0; ks < 2; ks++){
        #pragma unroll
        for (int mt = 0; mt < 4; mt++){
          bf16x8 kf = *(const bf16x8*)&ksp[(mt * 16 + l16) * LD + ks * 32 + quad * 8];
          sacc[mt] = __builtin_amdgcn_mfma_f32_16x16x32_bf16(kf, qf[ks], sacc[mt], 0, 0, 0);
        }
      }
      __builtin_amdgcn_s_setprio(0);

      bool diag = (kt == q0);
      int lq = w * 16 + l16;
      float sv[16]; float mx = -1e30f;
      #pragma unroll
      for (int mt = 0; mt < 4; mt++){
        #pragma unroll
        for (int r = 0; r < 4; r++){
          float s = sacc[mt][r];                 // already log2-domain (q pre-scaled)
          if (diag && (mt * 16 + quad * 4 + r > lq)) s = -1e30f;
          sv[mt * 4 + r] = s;
          mx = fmaxf(mx, s);
        }
      }
      mx = fmaxf(mx, __shfl_xor(mx, 16, 64));
      mx = fmaxf(mx, __shfl_xor(mx, 32, 64));
      // exact defer-max: if no row's max grew, alpha == 1 exactly -> skip rescale
      if (!__all(mx <= mprev)){
        float mnew = fmaxf(mprev, mx);
        float alpha = exp2f(mprev - mnew);
        mprev = mnew;
        lsum *= alpha;
        #pragma unroll
        for (int dt = 0; dt < 4; dt++) oacc[dt] *= alpha;
      }
      float rs = 0.f;
      #pragma unroll
      for (int mt = 0; mt < 4; mt++){
        float p0 = exp2f(sv[mt * 4 + 0] - mprev);
        float p1 = exp2f(sv[mt * 4 + 1] - mprev);
        float p2 = exp2f(sv[mt * 4 + 2] - mprev);
        float p3 = exp2f(sv[mt * 4 + 3] - mprev);
        rs += p0 + p1 + p2 + p3;
        union { uint2 u; __hip_bfloat162 h2[2]; } pk;
        pk.h2[0] = __float22bfloat162_rn(make_float2(p0, p1));
        pk.h2[1] = __float22bfloat162_rn(make_float2(p2, p3));
        *(uint2*)&Ps[(w * 16 + l16) * LD + mt * 16 + quad * 4] = pk.u;
      }
      rs += __shfl_xor(rs, 16, 64);
      rs += __shfl_xor(rs, 32, 64);
      lsum += rs;

      __builtin_amdgcn_s_setprio(1);
      #pragma unroll
      for (int ks = 0; ks < 2; ks++){
        bf16x8 pfr = *(const bf16x8*)&Ps[(w * 16 + l16) * LD + ks * 32 + quad * 8];
        #pragma unroll
        for (int dt = 0; dt < 4; dt++){
          bf16x8 vf = *(const bf16x8*)&vsp[(dt * 16 + l16) * LD + ks * 32 + quad * 8];
          oacc[dt] = __builtin_amdgcn_mfma_f32_16x16x32_bf16(vf, pfr, oacc[dt], 0, 0, 0);
        }
      }
      __builtin_amdgcn_s_setprio(0);

      // write next tile into the alternate buffer (vmcnt wait lands here, hidden)
      if (pfetch){
        int nb = cur ^ 1;
        *(uint4*)&Ks[nb][sr * LD + sc]     = kr0;
        *(uint4*)&Ks[nb][sr * LD + sc + 8] = kr1;
        *(uint4*)&Vs[nb][sr * LD + sc]     = vr0;
        *(uint4*)&Vs[nb][sr * LD + sc + 8] = vr1;
        cur = nb;
      }
      __syncthreads();   // single barrier per tile
    }

    float inv = 1.f / lsum;
    #pragma unroll
    for (int dt = 0; dt < 4; dt++){
      union { uint2 u; __hip_bfloat162 h2[2]; } ov;
      ov.h2[0] = __float22bfloat162_rn(make_float2(oacc[dt][0] * inv, oacc[dt][1] * inv));
      ov.h2[1] = __float22bfloat162_rn(make_float2(oacc[dt][2] * inv, oacc[dt][3] * inv));
      *(uint2*)(out + (bL + qrow) * 1024 + h * 64 + dt * 16 + quad * 4) = ov.u;
    }
  }
}

// ---------------- host launch ----------------
extern "C" void kernel_launch(void* const* d_in, const int* in_sizes, int n_in,
                              void* d_out, int out_size, void* d_ws, size_t ws_size,
                              hipStream_t stream){
  const float* x     = (const float*)d_in[0];
  const float* ln1_w = (const float*)d_in[1];
  const float* q_w   = (const float*)d_in[2];
  const float* kvd_w = (const float*)d_in[3];
  const float* kvn_w = (const float*)d_in[4];
  const float* kvu_w = (const float*)d_in[5];
  const float* o_w   = (const float*)d_in[6];
  const float* ln2_w = (const float*)d_in[7];
  const float* gate_w= (const float*)d_in[8];
  const float* sh_w1 = (const float*)d_in[9];
  const float* sh_w2 = (const float*)d_in[10];
  const float* sh_w3 = (const float*)d_in[11];
  const float* re_w1 = (const float*)d_in[12];
  const float* re_w2 = (const float*)d_in[13];
  const float* re_w3 = (const float*)d_in[14];
  float* out = (float*)d_out;

  char* wp = (char*)d_ws;
  auto alloc = [&](size_t bytes)->char*{
    char* p = wp; wp += (bytes + 255) & ~(size_t)255; return p;
  };
  u16* qkvdT = (u16*)alloc((size_t)1280 * 1024 * 2);   // q rows 0..1023, kvd 1024..1279
  u16* kvuT  = (u16*)alloc((size_t)2048 * 256 * 2);
  u16* oT    = (u16*)alloc((size_t)1024 * 1024 * 2);
  u16* sh13T = (u16*)alloc((size_t)2048 * 1024 * 2);   // interleaved w1/w3 rows
  u16* sh2T  = (u16*)alloc((size_t)1024 * 1024 * 2);
  u16* re13T = (u16*)alloc((size_t)8 * 2048 * 1024 * 2); // interleaved per expert
  u16* re2T  = (u16*)alloc((size_t)8 * 1024 * 1024 * 2);
  u16* xn    = (u16*)alloc((size_t)Tt * 1024 * 2);     // xn, later hn
  u16* qbuf  = (u16*)alloc((size_t)Tt * 1024 * 2);
  float* latpre = (float*)alloc((size_t)Tt * 256 * 4); // fp32 (routing-critical)
  u16* lat   = (u16*)alloc((size_t)Tt * 256 * 2);
  u16* kvbuf = (u16*)alloc((size_t)Tt * 2048 * 2);     // kv, later shared g [T,1024]
  u16* attnb = (u16*)alloc((size_t)Tt * 1024 * 2);
  float* hbuf = (float*)alloc((size_t)Tt * 1024 * 4);
  u16* vtb   = (u16*)alloc((size_t)Bb * Hh * 64 * Ll * 2);
  u16* gr    = (u16*)alloc((size_t)Tt * 2 * 1024 * 2); // routed g [2T,1024]
  int* counts = (int*)alloc(32);
  int* cur    = (int*)alloc(32);
  int* topi   = (int*)alloc((size_t)Tt * 2 * 4);
  float* topw = (float*)alloc((size_t)Tt * 2 * 4);
  int* entries= (int*)alloc((size_t)Tt * 2 * 4);
  float* ewt  = (float*)alloc((size_t)Tt * 2 * 4);
  (void)ws_size; (void)n_in; (void)in_sizes; (void)out_size;

  hipMemsetAsync(counts, 0, 32, stream);
  hipMemsetAsync(cur, 0, 32, stream);

  dim3 tb(32, 8);
  transpose5<<<dim3(32, 32, 5), tb, 0, stream>>>(q_w, o_w, sh_w1, sh_w3, sh_w2,
                                                 qkvdT, oT, sh13T, sh2T);
  transpose_conv<<<dim3(8, 32, 1), tb, 0, stream>>>(kvd_w, qkvdT, 1024, 256, 1024);
  transpose_conv<<<dim3(64, 8, 1), tb, 0, stream>>>(kvu_w, kvuT, 256, 2048, 0);
  transposeEx<<<dim3(32, 32, 24), tb, 0, stream>>>(re_w1, re_w3, re_w2, re13T, re2T);

  // xn = rmsnorm(x, ln1_w)
  rmsnorm_kernel<1024><<<Tt, 256, 0, stream>>>(x, ln1_w, xn);

  // [q(bf16, pre-scaled by QSCALE) | latent_pre(fp32)] = xn @ [q_w | kvd_w]
  gemm_bt<64,0,5><<<dim3(10, 64), 256, 0, stream>>>(xn, qkvdT, qbuf, nullptr,
      Tt, 1280, 1024, 1024, 1024, nullptr, nullptr, nullptr, latpre);
  rmsnorm_kernel<256><<<Tt, 256, 0, stream>>>(latpre, kvn_w, lat);
  // kv = latent @ kvu_w
  gemm_bt<128,0,0><<<dim3(16, 32), 256, 0, stream>>>(lat, kvuT, kvbuf, nullptr,
      Tt, 2048, 256, 256, 2048, nullptr, nullptr, nullptr, nullptr);
  // attention
  vt_kernel<<<dim3(32, 16, 2), 256, 0, stream>>>(kvbuf, vtb);
  attn_kernel<<<dim3(16, 16, 2), 256, 0, stream>>>(qbuf, kvbuf, vtb, attnb);
  // h = x + attn_out @ o_w
  gemm_bt<64,0,1><<<dim3(8, 64), 256, 0, stream>>>(attnb, oT, hbuf, x,
      Tt, 1024, 1024, 1024, 1024, nullptr, nullptr, nullptr, nullptr);
  // router (also writes hn into xn)
  router_kernel<<<Tt, 256, 0, stream>>>(hbuf, ln2_w, gate_w, out + (size_t)Tt * Dd,
                                        topi, topw, xn);
  hist_kernel<<<16, 256, 0, stream>>>(topi, counts);
  bucket_kernel<<<16, 256, 0, stream>>>(topi, topw, counts, cur, entries, ewt);

  // shared + routed up-projections (swiglu), one grouped relaxed-barrier launch:
  //   z=0..7: gr[entry-space] = swiglu(gather(hn) @ re13[e])
  //   z=8:    kvbuf = swiglu(hn @ sh13)
  gemm256_up<<<dim3(8, 16, 9), 512, 0, stream>>>(xn, sh13T, re13T, kvbuf, gr,
                                                 entries, counts);

  // out = h + g @ w2  (shared down)
  gemm_bt<64,0,1><<<dim3(8, 64), 256, 0, stream>>>(kvbuf, sh2T, out, hbuf,
      Tt, 1024, 1024, 1024, 1024, nullptr, nullptr, nullptr, nullptr);
  // routed down: out += w * (gr @ w2e)
  gemm_bt<128,2,4><<<dim3(8, 32, 8), 256, 0, stream>>>(gr, re2T, nullptr, nullptr,
      Tt, 1024, 1024, 1024, 1024, entries, ewt, counts, out);
}